// Round 8
// baseline (156.586 us; speedup 1.0000x reference)
//
#include <hip/hip_runtime.h>
#include <hip/hip_bf16.h>

// TriplesDistances: B=16, N=512, A=1024
// positions: float32 [B,N,3]; neighbors_j/k: int32 [B,N,A]; out: float32,
// (r_ij | r_ik | r_jk) each [B,N,A] concatenated flat.
//
// R6 post-mortem: perfect coalescing was neutral (~48us kernel) => latency
// of the per-chunk dependent chain (idx load -> LDS gather -> 40 VALU incl.
// libm sqrtf -> store), not line utilization. R7: (1) hoist all 8 idx loads
// ahead of compute (8 outstanding vmem/thread, one latency exposure per row);
// (2) raw v_sqrt_f32 via __builtin_amdgcn_sqrtf (1 instr, ~1 ULP; threshold
// is 0.159). Keep: float4 LDS, row-per-wave, lane*4 interleave, plain stores.

namespace {
constexpr int kB = 16;
constexpr int kN = 512;
constexpr int kA = 1024;
constexpr long long kBNA = (long long)kB * kN * kA;  // 8,388,608

typedef int   iv4 __attribute__((ext_vector_type(4)));
typedef float fv4 __attribute__((ext_vector_type(4)));
}  // namespace

__global__ __launch_bounds__(256, 8) void TriplesDistances_kernel(
    const float* __restrict__ pos,   // f32 [B*N*3]
    const int* __restrict__ nj,      // int32 [B*N*A]
    const int* __restrict__ nk,      // int32 [B*N*A]
    float* __restrict__ out)         // f32 [3*B*N*A]
{
    __shared__ fv4 spos[kN];  // 8 KB, float4-padded positions of this batch

    const int bid = blockIdx.x;        // 0..2047
    const int b   = bid >> 7;          // batch (128 blocks per batch)
    const int n0  = (bid & 127) << 2;  // first of 4 rows
    const int tid = threadIdx.x;

    // Stage batch-b positions: 1536 packed floats -> padded float4 layout.
    {
        const float* p = pos + (size_t)b * (kN * 3);
#pragma unroll
        for (int t = 0; t < 6; ++t) {
            const int e = tid + t * 256;
            const int a = e / 3;         // magic-mul, no HW div
            const int c = e - a * 3;
            ((float*)&spos[a])[c] = p[e];
        }
    }
    __syncthreads();

    const int wave = tid >> 6;          // 0..3 -> row n0+wave
    const int lane = tid & 63;
    const int row  = n0 + wave;
    const fv4 pi = spos[row];
    const float xi = pi.x, yi = pi.y, zi = pi.z;

    // Wave owns the full 1024-element row; 4 chunks of 256 elements.
    // Thread offset lane*4 => every iv4 load / fv4 store is 1 KB coalesced.
    const long long rowbase = ((long long)b * kN + row) * kA;
    const long long tbase   = rowbase + lane * 4;

    // Phase 1: issue ALL index loads (8 outstanding vmem ops/thread).
    iv4 jv[4], kv[4];
#pragma unroll
    for (int c = 0; c < 4; ++c) {
        jv[c] = *(const iv4*)(nj + tbase + c * 256);
        kv[c] = *(const iv4*)(nk + tbase + c * 256);
    }

    // Phase 2: gather + compute + store per chunk.
#pragma unroll
    for (int c = 0; c < 4; ++c) {
        const long long off = tbase + c * 256;
        const int js[4] = {jv[c].x, jv[c].y, jv[c].z, jv[c].w};
        const int ks[4] = {kv[c].x, kv[c].y, kv[c].z, kv[c].w};

        fv4 vij, vik, vjk;
        float* rij = (float*)&vij;
        float* rik = (float*)&vik;
        float* rjk = (float*)&vjk;
#pragma unroll
        for (int t = 0; t < 4; ++t) {
            const fv4 pj = spos[js[t]];   // 1x ds_read_b128
            const fv4 pk = spos[ks[t]];   // 1x ds_read_b128

            // safe_norm: v_sqrt_f32(0)=0 matches where(s>0, sqrt(s), 0)
            float dx = pj.x - xi, dy = pj.y - yi, dz = pj.z - zi;
            rij[t] = __builtin_amdgcn_sqrtf(dx * dx + dy * dy + dz * dz);

            dx = pk.x - xi; dy = pk.y - yi; dz = pk.z - zi;
            rik[t] = __builtin_amdgcn_sqrtf(dx * dx + dy * dy + dz * dz);

            dx = pj.x - pk.x; dy = pj.y - pk.y; dz = pj.z - pk.z;
            rjk[t] = __builtin_amdgcn_sqrtf(dx * dx + dy * dy + dz * dz);
        }

        // 1 KB coalesced plain stores (overwrite poison-dirty L2 lines).
        *(fv4*)(out + off)            = vij;
        *(fv4*)(out + kBNA + off)     = vik;
        *(fv4*)(out + 2 * kBNA + off) = vjk;
    }
}

extern "C" void kernel_launch(void* const* d_in, const int* in_sizes, int n_in,
                              void* d_out, int out_size, void* d_ws, size_t ws_size,
                              hipStream_t stream) {
    const float* pos = (const float*)d_in[0];
    const int* nj = (const int*)d_in[1];
    const int* nk = (const int*)d_in[2];
    float* out = (float*)d_out;

    // 4 rows per block (1 per wave): grid = B * N/4 = 2048 blocks, 256 threads.
    TriplesDistances_kernel<<<kB * (kN / 4), 256, 0, stream>>>(pos, nj, nk, out);
}